// Round 22
// baseline (537.995 us; speedup 1.0000x reference)
//
#include <hip/hip_runtime.h>

typedef unsigned short ushort;
typedef unsigned int uint;
typedef unsigned long long u64;

#define DEV __device__ __forceinline__

typedef __attribute__((ext_vector_type(4))) float f32x4;
typedef __bf16 bf16x8 __attribute__((ext_vector_type(8)));
typedef __attribute__((ext_vector_type(4))) ushort u16x4;
typedef __attribute__((ext_vector_type(8))) ushort u16x8;

static constexpr int B_ = 4, L_ = 4096, D_ = 512;
static constexpr long NE = (long)B_ * L_ * D_;      // 8388608

// ---------------- small helpers ----------------
DEV float b2f(ushort u) { return __uint_as_float(((uint)u) << 16); }
DEV ushort f2b(float f) {
    uint u = __float_as_uint(f);
    uint r = u + 0x7FFFu + ((u >> 16) & 1u);
    return (ushort)(r >> 16);
}
DEV uint mapF(float f) {
    uint b = __float_as_uint(f);
    return (b & 0x80000000u) ? ~b : (b | 0x80000000u);
}
DEV float unmapF(uint u) {
    uint b = (u & 0x80000000u) ? (u & 0x7FFFFFFFu) : ~u;
    return __uint_as_float(b);
}
DEV float rcp_(float x) { return __builtin_amdgcn_rcpf(x); }
DEV float fexp(float x) { return __builtin_amdgcn_exp2f(x * 1.44269504089f); }
DEV float sigm(float x) { return rcp_(1.f + fexp(-x)); }

DEV void gload16(const ushort* g, ushort* l) {
    __builtin_amdgcn_global_load_lds((const __attribute__((address_space(1))) void*)g,
                                     (__attribute__((address_space(3))) void*)l, 16, 0, 0);
}

// bijective XCD-chunked swizzle (m204)
DEV int xcd_swz(int b, int nwg) {
    int q = nwg >> 3, r = nwg & 7;
    int x = b & 7, i = b >> 3;
    int base = (x < r) ? x * (q + 1) : r * (q + 1) + (x - r) * q;
    return base + i;
}

// trigamma(t+1), t in (-1,1)
DEV float trigamma1p(float t) {
    float x = t + 1.f;
    float acc = 0.f;
#pragma unroll
    for (int k = 0; k < 6; k++) { float xx = x + (float)k; acc += rcp_(xx * xx); }
    float y = x + 6.f;
    float iy = rcp_(y), iy2 = iy * iy;
    return acc + iy * (1.f + iy * (0.5f + iy * (0.166666667f + iy2 * (-0.0333333333f + iy2 * 0.0238095238f))));
}
DEV float besselI1(float t) {
    float q = 0.25f * t * t;
    return 0.5f * t * (1.f + q * (0.5f + q * (0.0833333333f + q * (0.00694444444f + q * (3.47222222e-4f + q * 1.15740741e-5f)))));
}
DEV float rippleH(float u, float beta, float mix0, float mix1) {
    float t = beta * erff(u);
    float Tp = mix0 * trigamma1p(t) + mix1 * besselI1(t);
    float ep = 1.12837917f * fexp(-u * u);
    return beta * Tp * ep;
}

// ---------------- 128x128-tile GEMM core (2-phase dbuf) ----------------
DEV void gemm_core(const ushort* __restrict__ A, int lda,
                   const ushort* __restrict__ Bt, int ldb, int K,
                   ushort* __restrict__ Alds, ushort* __restrict__ Blds,
                   f32x4 (&acc)[4][4])
{
    const int tid = threadIdx.x;
    const int lane = tid & 63;
    const int wave = tid >> 6;
    const int wr = wave >> 1, wc = wave & 1;

    const int srow = wave * 16 + (lane >> 2);
    const int skc = (lane & 3) * 8;
    const ushort* Ag0 = A + (size_t)srow * lda + skc;
    const ushort* Ag1 = A + (size_t)(srow + 64) * lda + skc;
    const ushort* Bg0 = Bt + (size_t)srow * ldb + skc;
    const ushort* Bg1 = Bt + (size_t)(srow + 64) * ldb + skc;
    const int wb = wave * 512;

    const int ar = wr * 64 + (lane & 15);
    const int br = wc * 64 + (lane & 15);
    const int kk = (lane >> 4) * 8;

    gload16(Ag0, Alds + wb);
    gload16(Ag1, Alds + 2048 + wb);
    gload16(Bg0, Blds + wb);
    gload16(Bg1, Blds + 2048 + wb);
    __syncthreads();

    int cur = 0;
    for (int k0 = 0; k0 < K; k0 += 32) {
        const int nb = cur ^ 1;
        if (k0 + 32 < K) {
            gload16(Ag0 + k0 + 32, Alds + nb * 4096 + wb);
            gload16(Ag1 + k0 + 32, Alds + nb * 4096 + 2048 + wb);
            gload16(Bg0 + k0 + 32, Blds + nb * 4096 + wb);
            gload16(Bg1 + k0 + 32, Blds + nb * 4096 + 2048 + wb);
        }
        bf16x8 af[4], bfr[4];
#pragma unroll
        for (int mi = 0; mi < 4; mi++) af[mi] = *(const bf16x8*)&Alds[cur * 4096 + (ar + mi * 16) * 32 + kk];
#pragma unroll
        for (int ni = 0; ni < 4; ni++) bfr[ni] = *(const bf16x8*)&Blds[cur * 4096 + (br + ni * 16) * 32 + kk];
#pragma unroll
        for (int mi = 0; mi < 4; mi++)
#pragma unroll
            for (int ni = 0; ni < 4; ni++)
                acc[mi][ni] = __builtin_amdgcn_mfma_f32_16x16x32_bf16(af[mi], bfr[ni], acc[mi][ni], 0, 0, 0);
        __syncthreads();
        cur = nb;
    }
}

// shared bf16 tile epilogue: Cbase pre-offset to tile (row0,col0), relative write
DEV void write_tile_b16(ushort* Cbase, int ldc, f32x4 (&acc)[4][4]) {
    const int tid = threadIdx.x;
    const int lane = tid & 63;
    const int wave = tid >> 6;
    const int wr = wave >> 1, wc = wave & 1;
    const int ocol = wc * 64 + (lane & 15);
#pragma unroll
    for (int mi = 0; mi < 4; mi++) {
        const int rl = wr * 64 + mi * 16 + (lane >> 4) * 4;
#pragma unroll
        for (int j = 0; j < 4; j++)
#pragma unroll
            for (int ni = 0; ni < 4; ni++)
                Cbase[(size_t)(rl + j) * ldc + ocol + ni * 16] = f2b(acc[mi][ni][j]);
    }
}

// ---------------- 128x128 GEMM: C[M,N] = A[M,K] * Bt[N,K]^T ----------------
// MODE 0: f32 out; 1: bf16 out; 3: bf16 out scaled by rowScale[global row]
template <int MODE, bool DOMAX>
__global__ __launch_bounds__(256, 4) void gemm_bt(
    const ushort* __restrict__ A, int lda,
    const ushort* __restrict__ Bt, int ldb,
    void* __restrict__ Cv, int ldc, int K,
    const float* __restrict__ rowScale, u64* __restrict__ pmax)
{
    __shared__ ushort Alds[2 * 128 * 32];
    __shared__ ushort Blds[2 * 128 * 32];
    const int nwg = gridDim.x * gridDim.y;
    const int s = xcd_swz(blockIdx.y * gridDim.x + blockIdx.x, nwg);
    const int bx = s % gridDim.x, by = s / gridDim.x;
    const int row0 = by * 128, col0 = bx * 128;
    f32x4 acc[4][4] = {};
    gemm_core(A + (size_t)row0 * lda, lda, Bt + (size_t)col0 * ldb, ldb, K, Alds, Blds, acc);

    const int tid = threadIdx.x;
    const int lane = tid & 63;
    const int wave = tid >> 6;
    const int wr = wave >> 1, wc = wave & 1;
    const int ocol = col0 + wc * 64 + (lane & 15);
    u64 lp = 0;
#pragma unroll
    for (int mi = 0; mi < 4; mi++) {
        const int rbase = row0 + wr * 64 + mi * 16 + (lane >> 4) * 4;
#pragma unroll
        for (int j = 0; j < 4; j++) {
            float sc = (MODE == 3) ? rowScale[rbase + j] : 1.f;
#pragma unroll
            for (int ni = 0; ni < 4; ni++) {
                float v = acc[mi][ni][j] * sc;
                int cc = ocol + ni * 16;
                if (MODE == 0) ((float*)Cv)[(size_t)(rbase + j) * ldc + cc] = v;
                else ((ushort*)Cv)[(size_t)(rbase + j) * ldc + cc] = f2b(v);
                if (DOMAX) {
                    uint idx = (uint)((rbase + j) * ldc + cc);
                    u64 p = ((u64)mapF(v) << 32) | (u64)(~idx);
                    lp = (p > lp) ? p : lp;
                }
            }
        }
    }
    if (DOMAX) {
#pragma unroll
        for (int off = 32; off > 0; off >>= 1) {
            u64 o = __shfl_xor(lp, off);
            lp = (o > lp) ? o : lp;
        }
        if (lane == 0) atomicMax(pmax, lp);
    }
}

// ---------------- merged G1 (tmp = xb @ ASt) + gate GEMMs, 1536 blocks ----------------
__global__ __launch_bounds__(256, 4) void g1gate_k(
    const ushort* __restrict__ xb, const ushort* __restrict__ ASt, ushort* __restrict__ tmpb,
    const ushort* __restrict__ wigT, const ushort* __restrict__ wagT,
    ushort* __restrict__ gxab, ushort* __restrict__ gaab)
{
    __shared__ ushort Alds[2 * 128 * 32];
    __shared__ ushort Blds[2 * 128 * 32];
    const int flat = xcd_swz(blockIdx.x, 1536);
    f32x4 acc[4][4] = {};
    if (flat < 512) {
        const int bx = flat & 3, by = flat >> 2;
        gemm_core(xb + (size_t)(by * 128) * 512, 512, ASt + (size_t)(bx * 128) * 512, 512, 512, Alds, Blds, acc);
        write_tile_b16(tmpb + (size_t)(by * 128) * 512 + bx * 128, 512, acc);
    } else {
        const int f2 = flat - 512;
        const int which = f2 & 1, row = (f2 >> 1) & 127, h = f2 >> 8;
        gemm_core(xb + (size_t)row * 128 * 512 + h * 128, 512,
                  (which ? wagT : wigT) + (size_t)h * 16384, 128, 128, Alds, Blds, acc);
        write_tile_b16((which ? gaab : gxab) + (size_t)row * 128 * 512 + h * 128, 512, acc);
    }
}

// ---------------- 256x256-tile S-GEMM, BK=64 dbuf counted-vmcnt + T2 swizzle + exp epilogue ----------------
__global__ __launch_bounds__(512, 1) void gemm256_exp_k(
    const ushort* __restrict__ spP,   // [2][4096][512] bf16
    ushort* __restrict__ Sout,        // [2][4096][4096] bf16 (exp values)
    float* __restrict__ rowsum)       // [2][4096] f32, pre-zeroed
{
    __shared__ ushort Alds[2 * 256 * 64];   // 64 KB
    __shared__ ushort Blds[2 * 256 * 64];   // 64 KB (total 128 KB <= 160)
    const int z = blockIdx.z;
    const int nwg = gridDim.x * gridDim.y;
    const int s = xcd_swz(blockIdx.y * gridDim.x + blockIdx.x, nwg);
    const int bx = s % gridDim.x, by = s / gridDim.x;
    const int row0 = by * 256, col0 = bx * 256;
    const ushort* A = spP + (size_t)z * (4096 * 512) + (size_t)row0 * 512;
    const ushort* Bt = spP + (size_t)z * (4096 * 512) + (size_t)col0 * 512;

    const int tid = threadIdx.x;
    const int lane = tid & 63;
    const int wave = tid >> 6;          // 0..7
    const int wr = wave >> 2, wc = wave & 3;

    const int lrow = lane >> 3;                     // 0..7
    const int lchunk = (lane & 7) ^ lrow;           // T2 pre-swizzled source chunk
    const ushort* Asrc = A + (size_t)(wave * 32 + lrow) * 512 + lchunk * 8;
    const ushort* Bsrc = Bt + (size_t)(wave * 32 + lrow) * 512 + lchunk * 8;
    const int wlds = wave * 2048;                   // ushort offset of wave's 32-row slab

    const int ar = wr * 128 + (lane & 15);
    const int br = wc * 64 + (lane & 15);

    f32x4 acc[8][4] = {};

#define STG(kt, bf) do { \
    _Pragma("unroll") \
    for (int c = 0; c < 4; c++) { \
        gload16(Asrc + (size_t)c * 8 * 512 + (kt) * 64, Alds + (bf) * 16384 + wlds + c * 512); \
        gload16(Bsrc + (size_t)c * 8 * 512 + (kt) * 64, Blds + (bf) * 16384 + wlds + c * 512); \
    } } while (0)

    STG(0, 0);                          // prologue: K-tile 0 into buf0

    for (int kt = 0; kt < 8; kt++) {    // K = 512, 8 tiles of 64
        const int cb = kt & 1;
        if (kt < 7) STG(kt + 1, cb ^ 1);
        if (kt < 7) asm volatile("s_waitcnt vmcnt(8)" ::: "memory");
        else        asm volatile("s_waitcnt vmcnt(0)" ::: "memory");
        __builtin_amdgcn_s_barrier();
        asm volatile("" ::: "memory");
        __builtin_amdgcn_s_setprio(1);
#pragma unroll
        for (int ks = 0; ks < 2; ks++) {
            const int kc = ((ks * 4 + (lane >> 4)) ^ (lane & 7)) * 8;  // T2 swizzled read chunk
            bf16x8 af[8], bfr[4];
#pragma unroll
            for (int mi = 0; mi < 8; mi++) af[mi] = *(const bf16x8*)&Alds[cb * 16384 + (ar + mi * 16) * 64 + kc];
#pragma unroll
            for (int ni = 0; ni < 4; ni++) bfr[ni] = *(const bf16x8*)&Blds[cb * 16384 + (br + ni * 16) * 64 + kc];
#pragma unroll
            for (int mi = 0; mi < 8; mi++)
#pragma unroll
                for (int ni = 0; ni < 4; ni++)
                    acc[mi][ni] = __builtin_amdgcn_mfma_f32_16x16x32_bf16(af[mi], bfr[ni], acc[mi][ni], 0, 0, 0);
        }
        __builtin_amdgcn_s_setprio(0);
        asm volatile("s_waitcnt lgkmcnt(0)" ::: "memory");
        __builtin_amdgcn_s_barrier();
        asm volatile("" ::: "memory");
    }
#undef STG

    ushort* C = Sout + (size_t)z * 16777216;
    float* rs = rowsum + z * 4096;
    const float sc128 = 0.0883883476f;
    const int ocol = col0 + wc * 64 + (lane & 15);
#pragma unroll
    for (int mi = 0; mi < 8; mi++) {
        const int rbase = row0 + wr * 128 + mi * 16 + (lane >> 4) * 4;
#pragma unroll
        for (int j = 0; j < 4; j++) {
            float rsum = 0.f;
#pragma unroll
            for (int ni = 0; ni < 4; ni++) {
                float p = fexp(acc[mi][ni][j] * sc128);
                C[(size_t)(rbase + j) * 4096 + ocol + ni * 16] = f2b(p);
                rsum += p;
            }
#pragma unroll
            for (int off = 1; off < 16; off <<= 1) rsum += __shfl_xor(rsum, off);
            if ((lane & 15) == 0) atomicAdd(&rs[rbase + j], rsum);
        }
    }
}

// ---------------- PV split-K merged over batch pair: grid (4, 32, 8); z = zb*4 + ks ----------------
// XCD co-location: the 4 bx col-tiles sharing one P row-strip are mapped onto ONE XCD
// (hw dispatch round-robins flat id across XCDs; 128 blocks/z-slice, 128%8==0 keeps phase).
// per slice: x8 = hw&7 (XCD), i = hw>>3 (0..15); by = x8*4 + (i>>2), bx = i&3  (bijective)
__global__ __launch_bounds__(256, 4) void pv_split_k(const ushort* __restrict__ Spair, const ushort* __restrict__ VtBase,
                                                     ushort* __restrict__ part)
{
    __shared__ ushort Alds[2 * 128 * 32];
    __shared__ ushort Blds[2 * 128 * 32];
    const int zb = blockIdx.z >> 2, ks = blockIdx.z & 3;
    const ushort* P = Spair + (size_t)zb * 16777216;
    const ushort* Vt = VtBase + (size_t)zb * (512 * 4096);
    const int hw = blockIdx.y * gridDim.x + blockIdx.x;   // 0..127 per z-slice
    const int x8 = hw & 7, i = hw >> 3;
    const int by = x8 * 4 + (i >> 2);
    const int bx = i & 3;
    const int row0 = by * 128, col0 = bx * 128;
    f32x4 acc[4][4] = {};
    gemm_core(P + (size_t)row0 * 4096 + ks * 1024, 4096,
              Vt + (size_t)col0 * 4096 + ks * 1024, 4096, 1024, Alds, Blds, acc);

    write_tile_b16(part + (size_t)blockIdx.z * 2097152 + (size_t)row0 * 512 + col0, 512, acc);
}

// combine over batch pair: grid (128, 2); y = zb
__global__ __launch_bounds__(256) void pool_combine_k(const ushort* __restrict__ partB, const float* __restrict__ rsB,
                                                      uint* __restrict__ poolB)
{
    const int zb = blockIdx.y;
    const ushort* part = partB + (size_t)zb * 4 * 2097152;
    const float* rs = rsB + zb * 4096;
    uint* poolU = poolB + zb * 512;
    const int tid = threadIdx.x;
    const int l0 = blockIdx.x * 32;
    float m0 = -3.4e38f, m1 = -3.4e38f;
    for (int l = 0; l < 32; l++) {
        size_t off = (size_t)(l0 + l) * 512;
        float iv = rcp_(rs[l0 + l]);
        float s0 = 0.f, s1 = 0.f;
#pragma unroll
        for (int ks = 0; ks < 4; ks++) {
            s0 += b2f(part[(size_t)ks * 2097152 + off + tid]);
            s1 += b2f(part[(size_t)ks * 2097152 + off + tid + 256]);
        }
        m0 = fmaxf(m0, s0 * iv); m1 = fmaxf(m1, s1 * iv);
    }
    atomicMax(&poolU[tid], mapF(m0));
    atomicMax(&poolU[tid + 256], mapF(m1));
}

// ---------------- misc kernels ----------------
__global__ void convert_f2b_k(const float* __restrict__ s, ushort* __restrict__ d, long n4) {
    long i = (long)blockIdx.x * blockDim.x + threadIdx.x;
    long st = (long)gridDim.x * blockDim.x;
    for (; i < n4; i += st) {
        f32x4 v = ((const f32x4*)s)[i];
        u16x4 o;
        o[0] = f2b(v[0]); o[1] = f2b(v[1]); o[2] = f2b(v[2]); o[3] = f2b(v[3]);
        ((u16x4*)d)[i] = o;
    }
}

// 4 weight matrices + zero-init of poolU/pmax/rowsum/scal (folded init)
__global__ void convert_w4_k(const float* __restrict__ w0, const float* __restrict__ w1,
                             const float* __restrict__ w2, const float* __restrict__ w3,
                             ushort* __restrict__ dst,
                             uint* __restrict__ poolU, u64* __restrict__ pmax,
                             float* __restrict__ rowsum, float* __restrict__ scal) {
    const float* srcs[4] = {w0, w1, w2, w3};
    const float* s = srcs[blockIdx.y];
    ushort* d = dst + (size_t)blockIdx.y * 262144;
    int i = blockIdx.x * 256 + threadIdx.x;
    f32x4 v = ((const f32x4*)s)[i];
    u16x4 o;
    o[0] = f2b(v[0]); o[1] = f2b(v[1]); o[2] = f2b(v[2]); o[3] = f2b(v[3]);
    ((u16x4*)d)[i] = o;
    if (blockIdx.y == 0) {
        const int x = blockIdx.x;
        if (x < 32) {                                   // rowsum[16384]
            rowsum[x * 512 + threadIdx.x] = 0.f;
            rowsum[x * 512 + 256 + threadIdx.x] = 0.f;
        } else if (x == 32) {
            for (int k = threadIdx.x; k < 2048; k += 256) poolU[k] = 0u;
            if (threadIdx.x < 4) pmax[threadIdx.x] = 0ull;
            if (threadIdx.x < 64) scal[threadIdx.x] = 0.f;
        }
    }
}

template <bool SRCF32>
__global__ __launch_bounds__(256) void transpose_to_bf16(const void* __restrict__ srcv, ushort* __restrict__ dst, int R, int C) {
    __shared__ float tile[32][33];
    const int z = blockIdx.z;
    const float* sf = (const float*)srcv + (size_t)z * R * C;
    const ushort* sb = (const ushort*)srcv + (size_t)z * R * C;
    ushort* dz = dst + (size_t)z * R * C;
    const int tx = threadIdx.x & 31, ty = threadIdx.x >> 5;
    const int c = blockIdx.x * 32 + tx;
#pragma unroll
    for (int k = 0; k < 4; k++) {
        const int r = blockIdx.y * 32 + ty + k * 8;
        tile[ty + k * 8][tx] = SRCF32 ? sf[(size_t)r * C + c] : b2f(sb[(size_t)r * C + c]);
    }
    __syncthreads();
#pragma unroll
    for (int k = 0; k < 4; k++) {
        const int dr = blockIdx.x * 32 + ty + k * 8;
        const int dc = blockIdx.y * 32 + tx;
        dz[(size_t)dr * R + dc] = f2b(tile[tx][ty + k * 8]);
    }
}

__global__ __launch_bounds__(256) void transpose_gates_k(const float* __restrict__ wig, const float* __restrict__ wag,
                                                         ushort* __restrict__ wigT, ushort* __restrict__ wagT) {
    __shared__ float tile[32][33];
    const int which = blockIdx.z >> 2, h = blockIdx.z & 3;
    const float* src = (which ? wag : wig) + (size_t)h * 16384;
    ushort* dst = (which ? wagT : wigT) + (size_t)h * 16384;
    const int tx = threadIdx.x & 31, ty = threadIdx.x >> 5;
    const int c = blockIdx.x * 32 + tx;
#pragma unroll
    for (int k = 0; k < 4; k++) {
        const int r = blockIdx.y * 32 + ty + k * 8;
        tile[ty + k * 8][tx] = src[(size_t)r * 128 + c];
    }
    __syncthreads();
#pragma unroll
    for (int k = 0; k < 4; k++) {
        const int dr = blockIdx.x * 32 + ty + k * 8;
        const int dc = blockIdx.y * 32 + tx;
        dst[(size_t)dr * 128 + dc] = f2b(tile[tx][ty + k * 8]);
    }
}

__global__ void sentinel_k(float* o) { o[threadIdx.x] = 1.0e6f; }

// fused gates+gated
__global__ __launch_bounds__(256) void gates_gated_k(const float* __restrict__ x, const ushort* __restrict__ gxab,
                                                     const ushort* __restrict__ gaab, const float* __restrict__ a_param,
                                                     const uint* __restrict__ poolU, ushort* __restrict__ gatedb) {
    __shared__ float sp8[512];
    const int tid = threadIdx.x;
    for (int d = tid; d < 512; d += 256) {
        float a = a_param[d];
        sp8[d] = 8.f * (fmaxf(a, 0.f) + log1pf(expf(-fabsf(a))));
    }
    __syncthreads();
    long i = (long)blockIdx.x * blockDim.x + tid;
    long st = (long)gridDim.x * blockDim.x;
    const long n8 = NE >> 3;
    for (; i < n8; i += st) {
        u16x8 gx8 = ((const u16x8*)gxab)[i];
        u16x8 ga8 = ((const u16x8*)gaab)[i];
        f32x4 x0 = ((const f32x4*)x)[2 * i];
        f32x4 x1 = ((const f32x4*)x)[2 * i + 1];
        long e = i << 3;
        int b = (int)(e >> 21);
        int d0 = (int)(e & 511);
        u16x8 o;
#pragma unroll
        for (int j = 0; j < 8; j++) {
            float xv = (j < 4) ? x0[j] : x1[j - 4];
            float gx = sigm(b2f(gx8[j]));
            float ga = sigm(b2f(ga8[j]));
            float la = -sp8[d0 + j] * ga;
            float ea = fexp(la);
            float nx = xv * gx * sqrtf(fmaxf(1.f - fexp(2.f * la), 0.f));
            float pl = unmapF(poolU[b * 512 + d0 + j]);
            o[j] = f2b(ea * pl + nx);
        }
        ((u16x8*)gatedb)[i] = o;
    }
}

// ripple gradient base; M from packed pmax; d and gb are bf16, u16x8-vectorized (G13)
__global__ __launch_bounds__(256) void ripple_g_k(const ushort* __restrict__ d, ushort* __restrict__ gb, float* __restrict__ sspart,
                                                  const u64* __restrict__ pmax, const float* __restrict__ alpha_p,
                                                  const float* __restrict__ beta_p, const float* __restrict__ mix_p) {
    __shared__ float red[256];
    const int tid = threadIdx.x;
    const float M = unmapF((uint)(pmax[0] >> 32));
    const float alpha = alpha_p[0], beta = beta_p[0];
    float m0 = mix_p[0], m1 = mix_p[1];
    float mm = fmaxf(m0, m1);
    float e0 = fexp(m0 - mm), e1 = fexp(m1 - mm);
    float inv = rcp_(e0 + e1);
    float mix0 = e0 * inv, mix1 = e1 * inv;
    const float invMA = rcp_(M * alpha);
    float ss = 0.f;
    const long n8 = NE >> 3;            // 1048576 vec8 packets
    long i = (long)blockIdx.x * 256 + tid;
    const long stride = (long)gridDim.x * 256;
    for (; i < n8; i += stride) {
        u16x8 d8 = ((const u16x8*)d)[i];
        u16x8 o;
#pragma unroll
        for (int j = 0; j < 8; j++) {
            float dv = b2f(d8[j]);
            float H = rippleH(dv * invMA, beta, mix0, mix1);
            o[j] = f2b(H * invMA);
            ss += H * dv;
        }
        ((u16x8*)gb)[i] = o;
    }
    red[tid] = ss; __syncthreads();
    for (int s = 128; s > 0; s >>= 1) { if (tid < s) red[tid] += red[tid + s]; __syncthreads(); }
    if (tid == 0) sspart[blockIdx.x] = red[0];
}
__global__ __launch_bounds__(256) void redsum2_k(const float* __restrict__ part, int n, float* __restrict__ out) {
    __shared__ float red[256];
    const int tid = threadIdx.x;
    float s = 0.f;
    for (int i = tid; i < n; i += 256) s += part[i];
    red[tid] = s; __syncthreads();
    for (int q = 128; q > 0; q >>= 1) { if (tid < q) red[tid] += red[tid + q]; __syncthreads(); }
    if (tid == 0) out[0] = red[0];
}

// per-row (512) softmin, wave-per-row: 4 waves/block, lane loads u16x8 (64*8=512),
// shuffle-reduce min/sum — no LDS, no barriers; grid 4096
template <int GS>
__global__ __launch_bounds__(256) void ripple_softmax_k(const ushort* __restrict__ gb,
                                                        const u64* __restrict__ pmax,
                                                        const float* __restrict__ ssTot, const float* __restrict__ alpha_p,
                                                        const ushort* __restrict__ gatedb, ushort* __restrict__ outb) {
    const int tid = threadIdx.x;
    const int lane = tid & 63, wid = tid >> 6;
    const float M = unmapF((uint)(pmax[0] >> 32));
    const int amax = (int)(~(uint)(pmax[0] & 0xFFFFFFFFull));
    const float corr = ssTot[0] * rcp_(M * M * alpha_p[0]);
    const long row = (long)blockIdx.x * 4 + wid;
    const long base = row * 512 + lane * 8;
    u16x8 g8 = ((const u16x8*)gb)[base >> 3];
    float g[8];
    float mn = 3.4e38f;
#pragma unroll
    for (int j = 0; j < 8; j++) {
        float v = b2f(g8[j]);
        if ((int)(base + j) == amax) v -= corr;
        v = fminf(fmaxf(v, -1.f), 1.f);
        g[j] = v;
        mn = fminf(mn, v);
    }
#pragma unroll
    for (int off = 32; off > 0; off >>= 1) mn = fminf(mn, __shfl_xor(mn, off));
    float sum = 0.f;
#pragma unroll
    for (int j = 0; j < 8; j++) { g[j] = fexp(mn - g[j]); sum += g[j]; }
#pragma unroll
    for (int off = 32; off > 0; off >>= 1) sum += __shfl_xor(sum, off);
    const float inv = rcp_(sum);
    u16x8 o;
    if (GS) {
        u16x8 gt = ((const u16x8*)gatedb)[base >> 3];
#pragma unroll
        for (int j = 0; j < 8; j++) o[j] = f2b(b2f(gt[j]) * (g[j] * inv));
    } else {
#pragma unroll
        for (int j = 0; j < 8; j++) o[j] = f2b(g[j] * inv);
    }
    ((u16x8*)outb)[base >> 3] = o;
}

// token selection stage 1
__global__ __launch_bounds__(256) void ts1_k(const float* __restrict__ x, const float* __restrict__ cls_w,
                                             const float* __restrict__ cls_b, const float* __restrict__ tw,
                                             const float* __restrict__ prelu_a,
                                             float* __restrict__ combined, float* __restrict__ vals) {
    __shared__ float cw[2048];
    const int tid = threadIdx.x;
    for (int i = tid; i < 2048; i += 256) cw[i] = cls_w[i];
    __syncthreads();
    const int lane = tid & 63, wid = tid >> 6;
    const int row = blockIdx.x * 4 + wid;
    const float* xr = x + (size_t)row * 512 + lane * 8;
    float pa0 = 0, pa1 = 0, pa2 = 0, pa3 = 0;
#pragma unroll
    for (int j = 0; j < 8; j++) {
        float v = xr[j];
        int c = lane * 8 + j;
        pa0 += v * cw[c]; pa1 += v * cw[512 + c]; pa2 += v * cw[1024 + c]; pa3 += v * cw[1536 + c];
    }
#pragma unroll
    for (int o = 32; o > 0; o >>= 1) {
        pa0 += __shfl_down(pa0, o); pa1 += __shfl_down(pa1, o);
        pa2 += __shfl_down(pa2, o); pa3 += __shfl_down(pa3, o);
    }
    if (lane == 0) {
        float a = prelu_a[0];
        float sc[4] = {pa0, pa1, pa2, pa3};
        float comb = 0.f, vsum = 0.f;
#pragma unroll
        for (int s = 0; s < 4; s++) {
            float p = sc[s] + cls_b[s];
            p = (p >= 0.f) ? p : a * p;
            float cel = (p > 0.f) ? p : expm1f(p);
            float sil = p * sigm(p);
            float gel = 0.5f * p * (1.f + erff(p * 0.70710678f));
            float ts = cel * sil + gel;
            float ww = tw[s];
            float se = 1.05070099f * ((ww > 0.f) ? ww : 1.67326324f * expm1f(ww));
            comb += se * ts;
            vsum += ts;
        }
        combined[row] = comb;
        vals[row] = vsum;
    }
}

// ts2a: partial ranks. grid (16, 8, 4)
__global__ __launch_bounds__(256) void ts2a_k(const float* __restrict__ combined, int* __restrict__ rankp) {
    __shared__ float q[512];
    const int b = blockIdx.z;
    const int tid = threadIdx.x;
    const float* cr = combined + b * 4096;
    const int q0 = blockIdx.y * 512;
    for (int i = tid; i < 512; i += 256) q[i] = cr[q0 + i];
    __syncthreads();
    const int p = blockIdx.x * 256 + tid;
    const float cp = cr[p];
    const f32x4* q4 = (const f32x4*)q;
    int rank = 0;
#pragma unroll 8
    for (int i4 = 0; i4 < 128; i4++) {
        f32x4 v = q4[i4];
        int qb = q0 + i4 * 4;
        rank += (v[0] > cp) || (v[0] == cp && (qb + 0) < p);
        rank += (v[1] > cp) || (v[1] == cp && (qb + 1) < p);
        rank += (v[2] > cp) || (v[2] == cp && (qb + 2) < p);
        rank += (v[3] > cp) || (v[3] == cp && (qb + 3) < p);
    }
    rankp[((b * 8 + blockIdx.y) * 4096) + p] = rank;
}

// ts2b + fused block max/argmax over imp. grid (16, 4) = 64 blocks.
__global__ __launch_bounds__(256) void ts2b_k(const int* __restrict__ rankp, const float* __restrict__ vals,
                                              float* __restrict__ imp, float* __restrict__ bmax, int* __restrict__ bidx) {
    __shared__ float rv[256];
    __shared__ int ri[256];
    const int tid = threadIdx.x;
    const int b = blockIdx.y;
    const int p = blockIdx.x * 256 + tid;
    int rank = 0;
#pragma unroll
    for (int c = 0; c < 8; c++) rank += rankp[((b * 8 + c) * 4096) + p];
    const int gi = b * 4096 + p;
    const float v = 1.f + vals[b * 4096 + rank];
    imp[gi] = v;
    rv[tid] = v; ri[tid] = gi; __syncthreads();
    for (int s = 128; s > 0; s >>= 1) {
        if (tid < s) {
            float ov = rv[tid + s]; int oi = ri[tid + s];
            if (ov > rv[tid] || (ov == rv[tid] && oi < ri[tid])) { rv[tid] = ov; ri[tid] = oi; }
        }
        __syncthreads();
    }
    if (tid == 0) { bmax[b * 16 + blockIdx.x] = rv[0]; bidx[b * 16 + blockIdx.x] = ri[0]; }
}

// moe gradient base over n=65536; M reduced inline from bmax[64]
__global__ __launch_bounds__(256) void moe_g_k(const float* __restrict__ imp, float* __restrict__ gmoe,
                                               float* __restrict__ sspart, const float* __restrict__ bmax,
                                               const float* __restrict__ tsw, const float* __restrict__ tsa,
                                               const float* __restrict__ tsb, const float* __restrict__ tsmix) {
    __shared__ float red[256];
    const int tid = threadIdx.x;
    float M = -3.4e38f;
#pragma unroll
    for (int k = 0; k < 64; k++) M = fmaxf(M, bmax[k]);
    float w[4], invMA[4], invA[4];
    {
        float wm = fmaxf(fmaxf(tsw[0], tsw[1]), fmaxf(tsw[2], tsw[3]));
        float s = 0.f;
#pragma unroll
        for (int k = 0; k < 4; k++) { w[k] = fexp(tsw[k] - wm); s += w[k]; }
        float si = rcp_(s);
#pragma unroll
        for (int k = 0; k < 4; k++) { w[k] *= si; invMA[k] = rcp_(M * tsa[k]); invA[k] = rcp_(tsa[k]); }
    }
    const float beta = tsb[0];
    float m0 = tsmix[0], m1 = tsmix[1];
    float mm = fmaxf(m0, m1);
    float e0 = fexp(m0 - mm), e1 = fexp(m1 - mm);
    float minv = rcp_(e0 + e1);
    const float mix0 = e0 * minv, mix1 = e1 * minv;

    float ss = 0.f;
    int i = blockIdx.x * 256 + tid;
    const int stride = gridDim.x * 256;
    for (; i < 65536; i += stride) {
        float dv = imp[i];
        float gbv = 0.f;
#pragma unroll
        for (int s = 0; s < 4; s++) {
            float H = rippleH(dv * invMA[s], beta, mix0, mix1);
            gbv += w[s] * H * invMA[s];
            ss += w[s] * H * dv * invA[s];
        }
        gmoe[i] = gbv;
    }
    red[tid] = ss; __syncthreads();
    for (int s = 128; s > 0; s >>= 1) { if (tid < s) red[tid] += red[tid + s]; __syncthreads(); }
    if (tid == 0) sspart[blockIdx.x] = red[0];
}

// moe softmin per batch row (4096); M/amax reduced inline from bmax/bidx[64]; sums sspart[64] inline
__global__ __launch_bounds__(256) void moe_sel_k(const float* __restrict__ gmoe, const float* __restrict__ bmax,
                                                 const int* __restrict__ bidx, const float* __restrict__ sspart,
                                                 float* __restrict__ sel) {
    __shared__ float red[256];
    const int tid = threadIdx.x;
    const int b = blockIdx.x;
    float M = -3.4e38f; int amax = 0x7FFFFFFF;
#pragma unroll
    for (int k = 0; k < 64; k++) {
        float v = bmax[k]; int ix = bidx[k];
        if (v > M || (v == M && ix < amax)) { M = v; amax = ix; }
    }
    float ssTot = 0.f;
#pragma unroll
    for (int k = 0; k < 64; k++) ssTot += sspart[k];
    const float corr = ssTot * rcp_(M * M);
    float g[16];
    float mn = 3.4e38f;
#pragma unroll
    for (int k = 0; k < 16; k++) {
        int i = b * 4096 + tid + k * 256;
        float v = gmoe[i];
        if (i == amax) v -= corr;
        v = fminf(fmaxf(v, -1.f), 1.f);
        g[k] = v;
        mn = fminf(mn, v);
    }
    red[tid] = mn; __syncthreads();
    for (int s = 128; s > 0; s >>= 1) { if (tid < s) red[tid] = fminf(red[tid], red[tid + s]); __syncthreads(); }
    mn = red[0]; __syncthreads();
    float sum = 0.f;
#pragma unroll
    for (int k = 0; k < 16; k++) { g[k] = fexp(mn - g[k]); sum += g[k]; }
    red[tid] = sum; __syncthreads();
    for (int s = 128; s > 0; s >>= 1) { if (tid < s) red[tid] += red[tid + s]; __syncthreads(); }
    float inv = rcp_(red[0]);
#pragma unroll
    for (int k = 0; k < 16; k++) sel[b * 4096 + tid + k * 256] = 1.f + g[k] * inv;
}

// ---------------- workspace layout (bytes) ----------------
static constexpr size_t OFF_XB    = 0;                       // ushort NE (attn: pvpart lower half; later probs2b)
static constexpr size_t OFF_TMPB  = 16777216;                // ushort NE (attn: pvpart upper half; later gsb)
static constexpr size_t OFF_SPB   = 33554432;                // ushort NE
static constexpr size_t OFF_SPT   = 50331648;                // ushort NE   ([4][512][4096])
static constexpr size_t OFF_DBUF  = 67108864;                // Sexp pair z=0 (32MB) / d1,attn bf16 / rankp
static constexpr size_t OFF_HBUF  = 100663296;               // Sexp pair z=1 (32MB) / gb bf16
static constexpr size_t OFF_GATB  = 134217728;               // ushort NE
static constexpr size_t OFF_NXB   = 150994944;               // ushort NE   (gxab)
static constexpr size_t OFF_EAB   = 167772160;               // ushort NE   (gaab)
static constexpr size_t OFF_AST   = 184549376;               // 512*512 ushort
static constexpr size_t OFF_WSP   = 185073664;
static constexpr size_t OFF_WSIL  = 185597952;
static constexpr size_t OFF_WOH   = 186122240;
static constexpr size_t OFF_WOUT  = 186646528;
static constexpr size_t OFF_WIGT  = 187170816;
static constexpr size_t OFF_WAGT  = 187301888;
static constexpr size_t OFF_POOL  = 187432960;               // 2048 uint
static constexpr size_t OFF_SCAL  = 187441152;               // 64 float (+ pmax u64[4] at +128)
static constexpr size_t OFF_SCALI = 187441408;
static constexpr size_t OFF_BMAX  = 187441664;
static constexpr size_t OFF_BIDX  = 187449856;
static constexpr size_t OFF_SSP   = 187458048;
static constexpr size_t OFF_COMB  = 187466240;               // 65536 float (attn: rowsum[2][8192])
static constexpr size_t OFF_VALS  = 187728384;
static constexpr size_t OFF_IMP   = 187990528;
static constexpr size_t OFF_GMOE  = 188252672;
static constexpr size_t OFF_SEL   = 188514816;
static constexpr size_t WS_NEED   = 188776960;

extern "C" void kernel_launch(void* const* d_in, const int* in_sizes, int n_in,
                              void* d_out, int out_size, void* d_ws, size_t ws_size,
                              hipStream_t stream)
{
    (void)in_sizes; (void)n_in; (void)out_size;
    const float* x    = (const float*)d_in[0];
    const float* AS   = (const float*)d_in[1];
    const float* Wsp  = (const float*)d_in[2];
    const float* Wsil = (const float*)d_in[3];
    const float* Woh  = (const float*)d_in[4];
    const float* Wout = (const float*)d_in[5];
    const float* wig  = (const float*)d_in[6];
    const float* wag  = (const float*)d_in[7];
    const float* a_param = (const float*)d_in[8];
    const float* cls_w = (const float*)d_in[9];
    const float* cls_b = (const float*)d_in[10];
    const float* tokw  = (const float*)d_in[11];
    const float* prelu = (const float*)d_in[12];
    const float* tsw   = (const float*)d_in[13];
    const float* tsa   = (const float*)d_in[14];
    const float* tsb   = (const float*)d_in[15];
    const float* tsmix = (const float*)d_in[16];
    const float* p1a = (const float*)d_in[17];
    const float* p1b = (const float*)d_in[18];
    const float* p1m = (const float*)d_in[19];
    const float* p2a = (const float*)d_in[20];
    const float* p2b = (const float*)d_in[21];
    const float* p2m = (const float*)d_in[22];
    float* out = (float*)d_out;

    char* w = (char*)d_ws;
    if (ws_size < WS_NEED) { sentinel_k<<<1, 256, 0, stream>>>(out); return; }

    ushort* xb    = (ushort*)(w + OFF_XB);
    ushort* tmpb  = (ushort*)(w + OFF_TMPB);
    ushort* spb   = (ushort*)(w + OFF_SPB);
    ushort* spT   = (ushort*)(w + OFF_SPT);
    ushort* db    = (ushort*)(w + OFF_DBUF);   // bf16 d1/attn buffer (ripple input)
    ushort* gbb   = (ushort*)(w + OFF_HBUF);   // bf16 gradient base (ripple passes)
    ushort* Spair = (ushort*)(w + OFF_DBUF);   // Sexp for batch pair: z*16777216 ushorts (64MB)
    ushort* pvpart= (ushort*)(w + OFF_XB);     // bf16 partials: [2 zb][4 ks][4096][512] (33.5MB XB+TMPB)
    int*    rankp = (int*)(w + OFF_DBUF);      // ts2 only
    ushort* gatedb= (ushort*)(w + OFF_GATB);
    ushort* gxab  = (ushort*)(w + OFF_NXB);
    ushort* gaab  = (ushort*)(w + OFF_EAB);
    ushort* ASt   = (ushort*)(w + OFF_AST);
    ushort* Wspb  = (ushort*)(w + OFF_WSP);
    ushort* Wsilb = (ushort*)(w + OFF_WSIL);
    ushort* Wohb  = (ushort*)(w + OFF_WOH);
    ushort* Woutb = (ushort*)(w + OFF_WOUT);
    ushort* wigT  = (ushort*)(w + OFF_WIGT);
    ushort* wagT  = (ushort*)(w + OFF_WAGT);
    uint*   poolU = (uint*)(w + OFF_POOL);
    float*  scal  = (float*)(w + OFF_SCAL);
    u64*    pmax  = (u64*)(w + OFF_SCAL + 128);
    float*  bmax  = (float*)(w + OFF_BMAX);
    int*    bidx  = (int*)(w + OFF_BIDX);
    float*  sspart= (float*)(w + OFF_SSP);
    float*  comb  = (float*)(w + OFF_COMB);
    float*  rowsum= comb;                      // [2][8192] during attention
    float*  vals  = (float*)(w + OFF_VALS);
    float*  imp   = (float*)(w + OFF_IMP);
    float*  gmoe  = (float*)(w + OFF_GMOE);
    float*  sel   = (float*)(w + OFF_SEL);
    ushort* gsb     = tmpb;
    ushort* probs2b = xb;

    // ---- prep ----
    convert_f2b_k<<<2048, 256, 0, stream>>>(x, xb, NE >> 2);
    convert_w4_k<<<dim3(256, 4), 256, 0, stream>>>(Wsp, Wsil, Woh, Wout, Wspb, poolU, pmax, rowsum, scal);
    transpose_to_bf16<true><<<dim3(16, 16, 1), 256, 0, stream>>>(AS, ASt, 512, 512);
    transpose_gates_k<<<dim3(4, 4, 8), 256, 0, stream>>>(wig, wag, wigT, wagT);

    // ---- merged G1 (tmp = xb @ ASt) + gate pre-act GEMMs ----
    g1gate_k<<<1536, 256, 0, stream>>>(xb, ASt, tmpb, wigT, wagT, gxab, gaab);

    // ---- G2: spatial = tmp @ Wsp^T ----
    gemm_bt<1, false><<<dim3(4, 128), 256, 0, stream>>>(tmpb, 512, Wspb, 512, spb, 512, 512, nullptr, nullptr);

    // ---- attention pool: batch pairs; 3 launches per pair ----
    transpose_to_bf16<false><<<dim3(16, 128, 4), 256, 0, stream>>>(spb, spT, 4096, 512);
    for (int p = 0; p < 2; p++) {
        const ushort* spP = spb + (size_t)(2 * p) * L_ * D_;
        gemm256_exp_k<<<dim3(16, 16, 2), 512, 0, stream>>>(spP, Spair, rowsum + p * 8192);
        pv_split_k<<<dim3(4, 32, 8), 256, 0, stream>>>(Spair, spT + (size_t)(2 * p) * D_ * L_, pvpart);
        pool_combine_k<<<dim3(128, 2), 256, 0, stream>>>(pvpart, rowsum + p * 8192, poolU + 2 * p * 512);
    }

    // ---- fused gates+gated ----
    gates_gated_k<<<1024, 256, 0, stream>>>(x, gxab, gaab, a_param, poolU, gatedb);

    // ---- sparsity = ripple_act(gated @ Wsil^T) ; gs = gated * sparsity ----
    gemm_bt<1, true><<<dim3(4, 128), 256, 0, stream>>>(gatedb, 512, Wsilb, 512, db, 512, 512, nullptr, &pmax[0]);
    ripple_g_k<<<2048, 256, 0, stream>>>(db, gbb, sspart, &pmax[0], p1a, p1b, p1m);
    redsum2_k<<<1, 256, 0, stream>>>(sspart, 2048, &scal[1]);
    ripple_softmax_k<1><<<4096, 256, 0, stream>>>(gbb, &pmax[0], &scal[1], p1a, gatedb, gsb);

    // ---- token selection -> sel ----
    ts1_k<<<4096, 256, 0, stream>>>(x, cls_w, cls_b, tokw, prelu, comb, vals);
    ts2a_k<<<dim3(16, 8, 4), 256, 0, stream>>>(comb, rankp);
    ts2b_k<<<dim3(16, 4), 256, 0, stream>>>(rankp, vals, imp, bmax, bidx);
    moe_g_k<<<64, 256, 0, stream>>>(imp, gmoe, sspart, bmax, tsw, tsa, tsb, tsmix);
    moe_sel_k<<<4, 256, 0, stream>>>(gmoe, bmax, bidx, sspart, sel);

    // ---- attn = gs @ Woh^T, scaled by sel (fused max; bf16 out) ----
    gemm_bt<3, true><<<dim3(4, 128), 256, 0, stream>>>(gsb, 512, Wohb, 512, db, 512, 512, sel, &pmax[1]);

    // ---- out_probs = ripple_act(d2) ----
    ripple_g_k<<<2048, 256, 0, stream>>>(db, gbb, sspart, &pmax[1], p2a, p2b, p2m);
    redsum2_k<<<1, 256, 0, stream>>>(sspart, 2048, &scal[3]);
    ripple_softmax_k<0><<<4096, 256, 0, stream>>>(gbb, &pmax[1], &scal[3], p2a, nullptr, probs2b);

    // ---- out = probs @ Wout^T ----
    gemm_bt<0, false><<<dim3(4, 128), 256, 0, stream>>>(probs2b, 512, Woutb, 512, out, 512, 512, nullptr, nullptr);
}

// Round 23
// 531.445 us; speedup vs baseline: 1.0123x; 1.0123x over previous
//
#include <hip/hip_runtime.h>

typedef unsigned short ushort;
typedef unsigned int uint;
typedef unsigned long long u64;

#define DEV __device__ __forceinline__

typedef __attribute__((ext_vector_type(4))) float f32x4;
typedef __bf16 bf16x8 __attribute__((ext_vector_type(8)));
typedef __attribute__((ext_vector_type(4))) ushort u16x4;
typedef __attribute__((ext_vector_type(8))) ushort u16x8;

static constexpr int B_ = 4, L_ = 4096, D_ = 512;
static constexpr long NE = (long)B_ * L_ * D_;      // 8388608

// ---------------- small helpers ----------------
DEV float b2f(ushort u) { return __uint_as_float(((uint)u) << 16); }
DEV ushort f2b(float f) {
    uint u = __float_as_uint(f);
    uint r = u + 0x7FFFu + ((u >> 16) & 1u);
    return (ushort)(r >> 16);
}
DEV uint mapF(float f) {
    uint b = __float_as_uint(f);
    return (b & 0x80000000u) ? ~b : (b | 0x80000000u);
}
DEV float unmapF(uint u) {
    uint b = (u & 0x80000000u) ? (u & 0x7FFFFFFFu) : ~u;
    return __uint_as_float(b);
}
DEV float rcp_(float x) { return __builtin_amdgcn_rcpf(x); }
DEV float fexp(float x) { return __builtin_amdgcn_exp2f(x * 1.44269504089f); }
DEV float sigm(float x) { return rcp_(1.f + fexp(-x)); }

DEV void gload16(const ushort* g, ushort* l) {
    __builtin_amdgcn_global_load_lds((const __attribute__((address_space(1))) void*)g,
                                     (__attribute__((address_space(3))) void*)l, 16, 0, 0);
}

// bijective XCD-chunked swizzle (m204)
DEV int xcd_swz(int b, int nwg) {
    int q = nwg >> 3, r = nwg & 7;
    int x = b & 7, i = b >> 3;
    int base = (x < r) ? x * (q + 1) : r * (q + 1) + (x - r) * q;
    return base + i;
}

// trigamma(t+1), t in (-1,1)
DEV float trigamma1p(float t) {
    float x = t + 1.f;
    float acc = 0.f;
#pragma unroll
    for (int k = 0; k < 6; k++) { float xx = x + (float)k; acc += rcp_(xx * xx); }
    float y = x + 6.f;
    float iy = rcp_(y), iy2 = iy * iy;
    return acc + iy * (1.f + iy * (0.5f + iy * (0.166666667f + iy2 * (-0.0333333333f + iy2 * 0.0238095238f))));
}
DEV float besselI1(float t) {
    float q = 0.25f * t * t;
    return 0.5f * t * (1.f + q * (0.5f + q * (0.0833333333f + q * (0.00694444444f + q * (3.47222222e-4f + q * 1.15740741e-5f)))));
}
DEV float rippleH(float u, float beta, float mix0, float mix1) {
    float t = beta * erff(u);
    float Tp = mix0 * trigamma1p(t) + mix1 * besselI1(t);
    float ep = 1.12837917f * fexp(-u * u);
    return beta * Tp * ep;
}

// ---------------- 128x128-tile GEMM core (2-phase dbuf) ----------------
DEV void gemm_core(const ushort* __restrict__ A, int lda,
                   const ushort* __restrict__ Bt, int ldb, int K,
                   ushort* __restrict__ Alds, ushort* __restrict__ Blds,
                   f32x4 (&acc)[4][4])
{
    const int tid = threadIdx.x;
    const int lane = tid & 63;
    const int wave = tid >> 6;
    const int wr = wave >> 1, wc = wave & 1;

    const int srow = wave * 16 + (lane >> 2);
    const int skc = (lane & 3) * 8;
    const ushort* Ag0 = A + (size_t)srow * lda + skc;
    const ushort* Ag1 = A + (size_t)(srow + 64) * lda + skc;
    const ushort* Bg0 = Bt + (size_t)srow * ldb + skc;
    const ushort* Bg1 = Bt + (size_t)(srow + 64) * ldb + skc;
    const int wb = wave * 512;

    const int ar = wr * 64 + (lane & 15);
    const int br = wc * 64 + (lane & 15);
    const int kk = (lane >> 4) * 8;

    gload16(Ag0, Alds + wb);
    gload16(Ag1, Alds + 2048 + wb);
    gload16(Bg0, Blds + wb);
    gload16(Bg1, Blds + 2048 + wb);
    __syncthreads();

    int cur = 0;
    for (int k0 = 0; k0 < K; k0 += 32) {
        const int nb = cur ^ 1;
        if (k0 + 32 < K) {
            gload16(Ag0 + k0 + 32, Alds + nb * 4096 + wb);
            gload16(Ag1 + k0 + 32, Alds + nb * 4096 + 2048 + wb);
            gload16(Bg0 + k0 + 32, Blds + nb * 4096 + wb);
            gload16(Bg1 + k0 + 32, Blds + nb * 4096 + 2048 + wb);
        }
        bf16x8 af[4], bfr[4];
#pragma unroll
        for (int mi = 0; mi < 4; mi++) af[mi] = *(const bf16x8*)&Alds[cur * 4096 + (ar + mi * 16) * 32 + kk];
#pragma unroll
        for (int ni = 0; ni < 4; ni++) bfr[ni] = *(const bf16x8*)&Blds[cur * 4096 + (br + ni * 16) * 32 + kk];
#pragma unroll
        for (int mi = 0; mi < 4; mi++)
#pragma unroll
            for (int ni = 0; ni < 4; ni++)
                acc[mi][ni] = __builtin_amdgcn_mfma_f32_16x16x32_bf16(af[mi], bfr[ni], acc[mi][ni], 0, 0, 0);
        __syncthreads();
        cur = nb;
    }
}

// shared bf16 tile epilogue: Cbase pre-offset to tile (row0,col0), relative write
DEV void write_tile_b16(ushort* Cbase, int ldc, f32x4 (&acc)[4][4]) {
    const int tid = threadIdx.x;
    const int lane = tid & 63;
    const int wave = tid >> 6;
    const int wr = wave >> 1, wc = wave & 1;
    const int ocol = wc * 64 + (lane & 15);
#pragma unroll
    for (int mi = 0; mi < 4; mi++) {
        const int rl = wr * 64 + mi * 16 + (lane >> 4) * 4;
#pragma unroll
        for (int j = 0; j < 4; j++)
#pragma unroll
            for (int ni = 0; ni < 4; ni++)
                Cbase[(size_t)(rl + j) * ldc + ocol + ni * 16] = f2b(acc[mi][ni][j]);
    }
}

// ---------------- 128x128 GEMM: C[M,N] = A[M,K] * Bt[N,K]^T ----------------
// MODE 0: f32 out; 1: bf16 out; 3: bf16 out scaled by rowScale[global row]
template <int MODE, bool DOMAX>
__global__ __launch_bounds__(256, 4) void gemm_bt(
    const ushort* __restrict__ A, int lda,
    const ushort* __restrict__ Bt, int ldb,
    void* __restrict__ Cv, int ldc, int K,
    const float* __restrict__ rowScale, u64* __restrict__ pmax)
{
    __shared__ ushort Alds[2 * 128 * 32];
    __shared__ ushort Blds[2 * 128 * 32];
    const int nwg = gridDim.x * gridDim.y;
    const int s = xcd_swz(blockIdx.y * gridDim.x + blockIdx.x, nwg);
    const int bx = s % gridDim.x, by = s / gridDim.x;
    const int row0 = by * 128, col0 = bx * 128;
    f32x4 acc[4][4] = {};
    gemm_core(A + (size_t)row0 * lda, lda, Bt + (size_t)col0 * ldb, ldb, K, Alds, Blds, acc);

    const int tid = threadIdx.x;
    const int lane = tid & 63;
    const int wave = tid >> 6;
    const int wr = wave >> 1, wc = wave & 1;
    const int ocol = col0 + wc * 64 + (lane & 15);
    u64 lp = 0;
#pragma unroll
    for (int mi = 0; mi < 4; mi++) {
        const int rbase = row0 + wr * 64 + mi * 16 + (lane >> 4) * 4;
#pragma unroll
        for (int j = 0; j < 4; j++) {
            float sc = (MODE == 3) ? rowScale[rbase + j] : 1.f;
#pragma unroll
            for (int ni = 0; ni < 4; ni++) {
                float v = acc[mi][ni][j] * sc;
                int cc = ocol + ni * 16;
                if (MODE == 0) ((float*)Cv)[(size_t)(rbase + j) * ldc + cc] = v;
                else ((ushort*)Cv)[(size_t)(rbase + j) * ldc + cc] = f2b(v);
                if (DOMAX) {
                    uint idx = (uint)((rbase + j) * ldc + cc);
                    u64 p = ((u64)mapF(v) << 32) | (u64)(~idx);
                    lp = (p > lp) ? p : lp;
                }
            }
        }
    }
    if (DOMAX) {
#pragma unroll
        for (int off = 32; off > 0; off >>= 1) {
            u64 o = __shfl_xor(lp, off);
            lp = (o > lp) ? o : lp;
        }
        if (lane == 0) atomicMax(pmax, lp);
    }
}

// ---------------- merged G1 (tmp = xb @ ASt) + gate GEMMs, 1536 blocks ----------------
__global__ __launch_bounds__(256, 4) void g1gate_k(
    const ushort* __restrict__ xb, const ushort* __restrict__ ASt, ushort* __restrict__ tmpb,
    const ushort* __restrict__ wigT, const ushort* __restrict__ wagT,
    ushort* __restrict__ gxab, ushort* __restrict__ gaab)
{
    __shared__ ushort Alds[2 * 128 * 32];
    __shared__ ushort Blds[2 * 128 * 32];
    const int flat = xcd_swz(blockIdx.x, 1536);
    f32x4 acc[4][4] = {};
    if (flat < 512) {
        const int bx = flat & 3, by = flat >> 2;
        gemm_core(xb + (size_t)(by * 128) * 512, 512, ASt + (size_t)(bx * 128) * 512, 512, 512, Alds, Blds, acc);
        write_tile_b16(tmpb + (size_t)(by * 128) * 512 + bx * 128, 512, acc);
    } else {
        const int f2 = flat - 512;
        const int which = f2 & 1, row = (f2 >> 1) & 127, h = f2 >> 8;
        gemm_core(xb + (size_t)row * 128 * 512 + h * 128, 512,
                  (which ? wagT : wigT) + (size_t)h * 16384, 128, 128, Alds, Blds, acc);
        write_tile_b16((which ? gaab : gxab) + (size_t)row * 128 * 512 + h * 128, 512, acc);
    }
}

// ---------------- 256x256-tile S-GEMM, BK=64 dbuf counted-vmcnt + T2 swizzle + exp epilogue ----------------
__global__ __launch_bounds__(512, 1) void gemm256_exp_k(
    const ushort* __restrict__ spP,   // [2][4096][512] bf16
    ushort* __restrict__ Sout,        // [2][4096][4096] bf16 (exp values)
    float* __restrict__ rowsum)       // [2][4096] f32, pre-zeroed
{
    __shared__ ushort Alds[2 * 256 * 64];   // 64 KB
    __shared__ ushort Blds[2 * 256 * 64];   // 64 KB (total 128 KB <= 160)
    const int z = blockIdx.z;
    const int nwg = gridDim.x * gridDim.y;
    const int s = xcd_swz(blockIdx.y * gridDim.x + blockIdx.x, nwg);
    const int bx = s % gridDim.x, by = s / gridDim.x;
    const int row0 = by * 256, col0 = bx * 256;
    const ushort* A = spP + (size_t)z * (4096 * 512) + (size_t)row0 * 512;
    const ushort* Bt = spP + (size_t)z * (4096 * 512) + (size_t)col0 * 512;

    const int tid = threadIdx.x;
    const int lane = tid & 63;
    const int wave = tid >> 6;          // 0..7
    const int wr = wave >> 2, wc = wave & 3;

    const int lrow = lane >> 3;                     // 0..7
    const int lchunk = (lane & 7) ^ lrow;           // T2 pre-swizzled source chunk
    const ushort* Asrc = A + (size_t)(wave * 32 + lrow) * 512 + lchunk * 8;
    const ushort* Bsrc = Bt + (size_t)(wave * 32 + lrow) * 512 + lchunk * 8;
    const int wlds = wave * 2048;                   // ushort offset of wave's 32-row slab

    const int ar = wr * 128 + (lane & 15);
    const int br = wc * 64 + (lane & 15);

    f32x4 acc[8][4] = {};

#define STG(kt, bf) do { \
    _Pragma("unroll") \
    for (int c = 0; c < 4; c++) { \
        gload16(Asrc + (size_t)c * 8 * 512 + (kt) * 64, Alds + (bf) * 16384 + wlds + c * 512); \
        gload16(Bsrc + (size_t)c * 8 * 512 + (kt) * 64, Blds + (bf) * 16384 + wlds + c * 512); \
    } } while (0)

    STG(0, 0);                          // prologue: K-tile 0 into buf0

    for (int kt = 0; kt < 8; kt++) {    // K = 512, 8 tiles of 64
        const int cb = kt & 1;
        if (kt < 7) STG(kt + 1, cb ^ 1);
        if (kt < 7) asm volatile("s_waitcnt vmcnt(8)" ::: "memory");
        else        asm volatile("s_waitcnt vmcnt(0)" ::: "memory");
        __builtin_amdgcn_s_barrier();
        asm volatile("" ::: "memory");
        __builtin_amdgcn_s_setprio(1);
#pragma unroll
        for (int ks = 0; ks < 2; ks++) {
            const int kc = ((ks * 4 + (lane >> 4)) ^ (lane & 7)) * 8;  // T2 swizzled read chunk
            bf16x8 af[8], bfr[4];
#pragma unroll
            for (int mi = 0; mi < 8; mi++) af[mi] = *(const bf16x8*)&Alds[cb * 16384 + (ar + mi * 16) * 64 + kc];
#pragma unroll
            for (int ni = 0; ni < 4; ni++) bfr[ni] = *(const bf16x8*)&Blds[cb * 16384 + (br + ni * 16) * 64 + kc];
#pragma unroll
            for (int mi = 0; mi < 8; mi++)
#pragma unroll
                for (int ni = 0; ni < 4; ni++)
                    acc[mi][ni] = __builtin_amdgcn_mfma_f32_16x16x32_bf16(af[mi], bfr[ni], acc[mi][ni], 0, 0, 0);
        }
        __builtin_amdgcn_s_setprio(0);
        asm volatile("s_waitcnt lgkmcnt(0)" ::: "memory");
        __builtin_amdgcn_s_barrier();
        asm volatile("" ::: "memory");
    }
#undef STG

    ushort* C = Sout + (size_t)z * 16777216;
    float* rs = rowsum + z * 4096;
    const float sc128 = 0.0883883476f;
    const int ocol = col0 + wc * 64 + (lane & 15);
#pragma unroll
    for (int mi = 0; mi < 8; mi++) {
        const int rbase = row0 + wr * 128 + mi * 16 + (lane >> 4) * 4;
#pragma unroll
        for (int j = 0; j < 4; j++) {
            float rsum = 0.f;
#pragma unroll
            for (int ni = 0; ni < 4; ni++) {
                float p = fexp(acc[mi][ni][j] * sc128);
                C[(size_t)(rbase + j) * 4096 + ocol + ni * 16] = f2b(p);
                rsum += p;
            }
#pragma unroll
            for (int off = 1; off < 16; off <<= 1) rsum += __shfl_xor(rsum, off);
            if ((lane & 15) == 0) atomicAdd(&rs[rbase + j], rsum);
        }
    }
}

// ---------------- PV split-K merged over batch pair: grid (4, 32, 8); z = zb*4 + ks ----------------
// partials bf16: part[(zb*4+ks)][4096][512]  (m204 swizzle; R22's XCD co-location probe was null/-)
__global__ __launch_bounds__(256, 4) void pv_split_k(const ushort* __restrict__ Spair, const ushort* __restrict__ VtBase,
                                                     ushort* __restrict__ part)
{
    __shared__ ushort Alds[2 * 128 * 32];
    __shared__ ushort Blds[2 * 128 * 32];
    const int zb = blockIdx.z >> 2, ks = blockIdx.z & 3;
    const ushort* P = Spair + (size_t)zb * 16777216;
    const ushort* Vt = VtBase + (size_t)zb * (512 * 4096);
    const int nwg = gridDim.x * gridDim.y;
    const int s = xcd_swz(blockIdx.y * gridDim.x + blockIdx.x, nwg);
    const int bx = s % gridDim.x, by = s / gridDim.x;
    const int row0 = by * 128, col0 = bx * 128;
    f32x4 acc[4][4] = {};
    gemm_core(P + (size_t)row0 * 4096 + ks * 1024, 4096,
              Vt + (size_t)col0 * 4096 + ks * 1024, 4096, 1024, Alds, Blds, acc);

    write_tile_b16(part + (size_t)blockIdx.z * 2097152 + (size_t)row0 * 512 + col0, 512, acc);
}

// combine over batch pair: grid (128, 2); y = zb
__global__ __launch_bounds__(256) void pool_combine_k(const ushort* __restrict__ partB, const float* __restrict__ rsB,
                                                      uint* __restrict__ poolB)
{
    const int zb = blockIdx.y;
    const ushort* part = partB + (size_t)zb * 4 * 2097152;
    const float* rs = rsB + zb * 4096;
    uint* poolU = poolB + zb * 512;
    const int tid = threadIdx.x;
    const int l0 = blockIdx.x * 32;
    float m0 = -3.4e38f, m1 = -3.4e38f;
    for (int l = 0; l < 32; l++) {
        size_t off = (size_t)(l0 + l) * 512;
        float iv = rcp_(rs[l0 + l]);
        float s0 = 0.f, s1 = 0.f;
#pragma unroll
        for (int ks = 0; ks < 4; ks++) {
            s0 += b2f(part[(size_t)ks * 2097152 + off + tid]);
            s1 += b2f(part[(size_t)ks * 2097152 + off + tid + 256]);
        }
        m0 = fmaxf(m0, s0 * iv); m1 = fmaxf(m1, s1 * iv);
    }
    atomicMax(&poolU[tid], mapF(m0));
    atomicMax(&poolU[tid + 256], mapF(m1));
}

// ---------------- misc kernels ----------------
__global__ void convert_f2b_k(const float* __restrict__ s, ushort* __restrict__ d, long n4) {
    long i = (long)blockIdx.x * blockDim.x + threadIdx.x;
    long st = (long)gridDim.x * blockDim.x;
    for (; i < n4; i += st) {
        f32x4 v = ((const f32x4*)s)[i];
        u16x4 o;
        o[0] = f2b(v[0]); o[1] = f2b(v[1]); o[2] = f2b(v[2]); o[3] = f2b(v[3]);
        ((u16x4*)d)[i] = o;
    }
}

// 4 weight matrices + zero-init of poolU/pmax/rowsum/scal (folded init)
__global__ void convert_w4_k(const float* __restrict__ w0, const float* __restrict__ w1,
                             const float* __restrict__ w2, const float* __restrict__ w3,
                             ushort* __restrict__ dst,
                             uint* __restrict__ poolU, u64* __restrict__ pmax,
                             float* __restrict__ rowsum, float* __restrict__ scal) {
    const float* srcs[4] = {w0, w1, w2, w3};
    const float* s = srcs[blockIdx.y];
    ushort* d = dst + (size_t)blockIdx.y * 262144;
    int i = blockIdx.x * 256 + threadIdx.x;
    f32x4 v = ((const f32x4*)s)[i];
    u16x4 o;
    o[0] = f2b(v[0]); o[1] = f2b(v[1]); o[2] = f2b(v[2]); o[3] = f2b(v[3]);
    ((u16x4*)d)[i] = o;
    if (blockIdx.y == 0) {
        const int x = blockIdx.x;
        if (x < 32) {                                   // rowsum[16384]
            rowsum[x * 512 + threadIdx.x] = 0.f;
            rowsum[x * 512 + 256 + threadIdx.x] = 0.f;
        } else if (x == 32) {
            for (int k = threadIdx.x; k < 2048; k += 256) poolU[k] = 0u;
            if (threadIdx.x < 4) pmax[threadIdx.x] = 0ull;
            if (threadIdx.x < 64) scal[threadIdx.x] = 0.f;
        }
    }
}

template <bool SRCF32>
__global__ __launch_bounds__(256) void transpose_to_bf16(const void* __restrict__ srcv, ushort* __restrict__ dst, int R, int C) {
    __shared__ float tile[32][33];
    const int z = blockIdx.z;
    const float* sf = (const float*)srcv + (size_t)z * R * C;
    const ushort* sb = (const ushort*)srcv + (size_t)z * R * C;
    ushort* dz = dst + (size_t)z * R * C;
    const int tx = threadIdx.x & 31, ty = threadIdx.x >> 5;
    const int c = blockIdx.x * 32 + tx;
#pragma unroll
    for (int k = 0; k < 4; k++) {
        const int r = blockIdx.y * 32 + ty + k * 8;
        tile[ty + k * 8][tx] = SRCF32 ? sf[(size_t)r * C + c] : b2f(sb[(size_t)r * C + c]);
    }
    __syncthreads();
#pragma unroll
    for (int k = 0; k < 4; k++) {
        const int dr = blockIdx.x * 32 + ty + k * 8;
        const int dc = blockIdx.y * 32 + tx;
        dz[(size_t)dr * R + dc] = f2b(tile[tx][ty + k * 8]);
    }
}

__global__ __launch_bounds__(256) void transpose_gates_k(const float* __restrict__ wig, const float* __restrict__ wag,
                                                         ushort* __restrict__ wigT, ushort* __restrict__ wagT) {
    __shared__ float tile[32][33];
    const int which = blockIdx.z >> 2, h = blockIdx.z & 3;
    const float* src = (which ? wag : wig) + (size_t)h * 16384;
    ushort* dst = (which ? wagT : wigT) + (size_t)h * 16384;
    const int tx = threadIdx.x & 31, ty = threadIdx.x >> 5;
    const int c = blockIdx.x * 32 + tx;
#pragma unroll
    for (int k = 0; k < 4; k++) {
        const int r = blockIdx.y * 32 + ty + k * 8;
        tile[ty + k * 8][tx] = src[(size_t)r * 128 + c];
    }
    __syncthreads();
#pragma unroll
    for (int k = 0; k < 4; k++) {
        const int dr = blockIdx.x * 32 + ty + k * 8;
        const int dc = blockIdx.y * 32 + tx;
        dst[(size_t)dr * 128 + dc] = f2b(tile[tx][ty + k * 8]);
    }
}

__global__ void sentinel_k(float* o) { o[threadIdx.x] = 1.0e6f; }

// fused gates+gated
__global__ __launch_bounds__(256) void gates_gated_k(const float* __restrict__ x, const ushort* __restrict__ gxab,
                                                     const ushort* __restrict__ gaab, const float* __restrict__ a_param,
                                                     const uint* __restrict__ poolU, ushort* __restrict__ gatedb) {
    __shared__ float sp8[512];
    const int tid = threadIdx.x;
    for (int d = tid; d < 512; d += 256) {
        float a = a_param[d];
        sp8[d] = 8.f * (fmaxf(a, 0.f) + log1pf(expf(-fabsf(a))));
    }
    __syncthreads();
    long i = (long)blockIdx.x * blockDim.x + tid;
    long st = (long)gridDim.x * blockDim.x;
    const long n8 = NE >> 3;
    for (; i < n8; i += st) {
        u16x8 gx8 = ((const u16x8*)gxab)[i];
        u16x8 ga8 = ((const u16x8*)gaab)[i];
        f32x4 x0 = ((const f32x4*)x)[2 * i];
        f32x4 x1 = ((const f32x4*)x)[2 * i + 1];
        long e = i << 3;
        int b = (int)(e >> 21);
        int d0 = (int)(e & 511);
        u16x8 o;
#pragma unroll
        for (int j = 0; j < 8; j++) {
            float xv = (j < 4) ? x0[j] : x1[j - 4];
            float gx = sigm(b2f(gx8[j]));
            float ga = sigm(b2f(ga8[j]));
            float la = -sp8[d0 + j] * ga;
            float ea = fexp(la);
            float nx = xv * gx * sqrtf(fmaxf(1.f - fexp(2.f * la), 0.f));
            float pl = unmapF(poolU[b * 512 + d0 + j]);
            o[j] = f2b(ea * pl + nx);
        }
        ((u16x8*)gatedb)[i] = o;
    }
}

// ripple gradient base; M from packed pmax; d and gb are bf16, u16x8-vectorized (G13)
__global__ __launch_bounds__(256) void ripple_g_k(const ushort* __restrict__ d, ushort* __restrict__ gb, float* __restrict__ sspart,
                                                  const u64* __restrict__ pmax, const float* __restrict__ alpha_p,
                                                  const float* __restrict__ beta_p, const float* __restrict__ mix_p) {
    __shared__ float red[256];
    const int tid = threadIdx.x;
    const float M = unmapF((uint)(pmax[0] >> 32));
    const float alpha = alpha_p[0], beta = beta_p[0];
    float m0 = mix_p[0], m1 = mix_p[1];
    float mm = fmaxf(m0, m1);
    float e0 = fexp(m0 - mm), e1 = fexp(m1 - mm);
    float inv = rcp_(e0 + e1);
    float mix0 = e0 * inv, mix1 = e1 * inv;
    const float invMA = rcp_(M * alpha);
    float ss = 0.f;
    const long n8 = NE >> 3;            // 1048576 vec8 packets
    long i = (long)blockIdx.x * 256 + tid;
    const long stride = (long)gridDim.x * 256;
    for (; i < n8; i += stride) {
        u16x8 d8 = ((const u16x8*)d)[i];
        u16x8 o;
#pragma unroll
        for (int j = 0; j < 8; j++) {
            float dv = b2f(d8[j]);
            float H = rippleH(dv * invMA, beta, mix0, mix1);
            o[j] = f2b(H * invMA);
            ss += H * dv;
        }
        ((u16x8*)gb)[i] = o;
    }
    red[tid] = ss; __syncthreads();
    for (int s = 128; s > 0; s >>= 1) { if (tid < s) red[tid] += red[tid + s]; __syncthreads(); }
    if (tid == 0) sspart[blockIdx.x] = red[0];
}
__global__ __launch_bounds__(256) void redsum2_k(const float* __restrict__ part, int n, float* __restrict__ out) {
    __shared__ float red[256];
    const int tid = threadIdx.x;
    float s = 0.f;
    for (int i = tid; i < n; i += 256) s += part[i];
    red[tid] = s; __syncthreads();
    for (int q = 128; q > 0; q >>= 1) { if (tid < q) red[tid] += red[tid + q]; __syncthreads(); }
    if (tid == 0) out[0] = red[0];
}

// per-row (512) softmin, wave-per-row: 4 waves/block, lane loads u16x8 (64*8=512),
// shuffle-reduce min/sum — no LDS, no barriers; grid 4096
template <int GS>
__global__ __launch_bounds__(256) void ripple_softmax_k(const ushort* __restrict__ gb,
                                                        const u64* __restrict__ pmax,
                                                        const float* __restrict__ ssTot, const float* __restrict__ alpha_p,
                                                        const ushort* __restrict__ gatedb, ushort* __restrict__ outb) {
    const int tid = threadIdx.x;
    const int lane = tid & 63, wid = tid >> 6;
    const float M = unmapF((uint)(pmax[0] >> 32));
    const int amax = (int)(~(uint)(pmax[0] & 0xFFFFFFFFull));
    const float corr = ssTot[0] * rcp_(M * M * alpha_p[0]);
    const long row = (long)blockIdx.x * 4 + wid;
    const long base = row * 512 + lane * 8;
    u16x8 g8 = ((const u16x8*)gb)[base >> 3];
    float g[8];
    float mn = 3.4e38f;
#pragma unroll
    for (int j = 0; j < 8; j++) {
        float v = b2f(g8[j]);
        if ((int)(base + j) == amax) v -= corr;
        v = fminf(fmaxf(v, -1.f), 1.f);
        g[j] = v;
        mn = fminf(mn, v);
    }
#pragma unroll
    for (int off = 32; off > 0; off >>= 1) mn = fminf(mn, __shfl_xor(mn, off));
    float sum = 0.f;
#pragma unroll
    for (int j = 0; j < 8; j++) { g[j] = fexp(mn - g[j]); sum += g[j]; }
#pragma unroll
    for (int off = 32; off > 0; off >>= 1) sum += __shfl_xor(sum, off);
    const float inv = rcp_(sum);
    u16x8 o;
    if (GS) {
        u16x8 gt = ((const u16x8*)gatedb)[base >> 3];
#pragma unroll
        for (int j = 0; j < 8; j++) o[j] = f2b(b2f(gt[j]) * (g[j] * inv));
    } else {
#pragma unroll
        for (int j = 0; j < 8; j++) o[j] = f2b(g[j] * inv);
    }
    ((u16x8*)outb)[base >> 3] = o;
}

// token selection stage 1
__global__ __launch_bounds__(256) void ts1_k(const float* __restrict__ x, const float* __restrict__ cls_w,
                                             const float* __restrict__ cls_b, const float* __restrict__ tw,
                                             const float* __restrict__ prelu_a,
                                             float* __restrict__ combined, float* __restrict__ vals) {
    __shared__ float cw[2048];
    const int tid = threadIdx.x;
    for (int i = tid; i < 2048; i += 256) cw[i] = cls_w[i];
    __syncthreads();
    const int lane = tid & 63, wid = tid >> 6;
    const int row = blockIdx.x * 4 + wid;
    const float* xr = x + (size_t)row * 512 + lane * 8;
    float pa0 = 0, pa1 = 0, pa2 = 0, pa3 = 0;
#pragma unroll
    for (int j = 0; j < 8; j++) {
        float v = xr[j];
        int c = lane * 8 + j;
        pa0 += v * cw[c]; pa1 += v * cw[512 + c]; pa2 += v * cw[1024 + c]; pa3 += v * cw[1536 + c];
    }
#pragma unroll
    for (int o = 32; o > 0; o >>= 1) {
        pa0 += __shfl_down(pa0, o); pa1 += __shfl_down(pa1, o);
        pa2 += __shfl_down(pa2, o); pa3 += __shfl_down(pa3, o);
    }
    if (lane == 0) {
        float a = prelu_a[0];
        float sc[4] = {pa0, pa1, pa2, pa3};
        float comb = 0.f, vsum = 0.f;
#pragma unroll
        for (int s = 0; s < 4; s++) {
            float p = sc[s] + cls_b[s];
            p = (p >= 0.f) ? p : a * p;
            float cel = (p > 0.f) ? p : expm1f(p);
            float sil = p * sigm(p);
            float gel = 0.5f * p * (1.f + erff(p * 0.70710678f));
            float ts = cel * sil + gel;
            float ww = tw[s];
            float se = 1.05070099f * ((ww > 0.f) ? ww : 1.67326324f * expm1f(ww));
            comb += se * ts;
            vsum += ts;
        }
        combined[row] = comb;
        vals[row] = vsum;
    }
}

// ts2a: partial ranks. grid (16, 8, 4)
__global__ __launch_bounds__(256) void ts2a_k(const float* __restrict__ combined, int* __restrict__ rankp) {
    __shared__ float q[512];
    const int b = blockIdx.z;
    const int tid = threadIdx.x;
    const float* cr = combined + b * 4096;
    const int q0 = blockIdx.y * 512;
    for (int i = tid; i < 512; i += 256) q[i] = cr[q0 + i];
    __syncthreads();
    const int p = blockIdx.x * 256 + tid;
    const float cp = cr[p];
    const f32x4* q4 = (const f32x4*)q;
    int rank = 0;
#pragma unroll 8
    for (int i4 = 0; i4 < 128; i4++) {
        f32x4 v = q4[i4];
        int qb = q0 + i4 * 4;
        rank += (v[0] > cp) || (v[0] == cp && (qb + 0) < p);
        rank += (v[1] > cp) || (v[1] == cp && (qb + 1) < p);
        rank += (v[2] > cp) || (v[2] == cp && (qb + 2) < p);
        rank += (v[3] > cp) || (v[3] == cp && (qb + 3) < p);
    }
    rankp[((b * 8 + blockIdx.y) * 4096) + p] = rank;
}

// ts2b + fused block max/argmax over imp. grid (16, 4) = 64 blocks.
__global__ __launch_bounds__(256) void ts2b_k(const int* __restrict__ rankp, const float* __restrict__ vals,
                                              float* __restrict__ imp, float* __restrict__ bmax, int* __restrict__ bidx) {
    __shared__ float rv[256];
    __shared__ int ri[256];
    const int tid = threadIdx.x;
    const int b = blockIdx.y;
    const int p = blockIdx.x * 256 + tid;
    int rank = 0;
#pragma unroll
    for (int c = 0; c < 8; c++) rank += rankp[((b * 8 + c) * 4096) + p];
    const int gi = b * 4096 + p;
    const float v = 1.f + vals[b * 4096 + rank];
    imp[gi] = v;
    rv[tid] = v; ri[tid] = gi; __syncthreads();
    for (int s = 128; s > 0; s >>= 1) {
        if (tid < s) {
            float ov = rv[tid + s]; int oi = ri[tid + s];
            if (ov > rv[tid] || (ov == rv[tid] && oi < ri[tid])) { rv[tid] = ov; ri[tid] = oi; }
        }
        __syncthreads();
    }
    if (tid == 0) { bmax[b * 16 + blockIdx.x] = rv[0]; bidx[b * 16 + blockIdx.x] = ri[0]; }
}

// moe gradient base over n=65536; M reduced inline from bmax[64]
__global__ __launch_bounds__(256) void moe_g_k(const float* __restrict__ imp, float* __restrict__ gmoe,
                                               float* __restrict__ sspart, const float* __restrict__ bmax,
                                               const float* __restrict__ tsw, const float* __restrict__ tsa,
                                               const float* __restrict__ tsb, const float* __restrict__ tsmix) {
    __shared__ float red[256];
    const int tid = threadIdx.x;
    float M = -3.4e38f;
#pragma unroll
    for (int k = 0; k < 64; k++) M = fmaxf(M, bmax[k]);
    float w[4], invMA[4], invA[4];
    {
        float wm = fmaxf(fmaxf(tsw[0], tsw[1]), fmaxf(tsw[2], tsw[3]));
        float s = 0.f;
#pragma unroll
        for (int k = 0; k < 4; k++) { w[k] = fexp(tsw[k] - wm); s += w[k]; }
        float si = rcp_(s);
#pragma unroll
        for (int k = 0; k < 4; k++) { w[k] *= si; invMA[k] = rcp_(M * tsa[k]); invA[k] = rcp_(tsa[k]); }
    }
    const float beta = tsb[0];
    float m0 = tsmix[0], m1 = tsmix[1];
    float mm = fmaxf(m0, m1);
    float e0 = fexp(m0 - mm), e1 = fexp(m1 - mm);
    float minv = rcp_(e0 + e1);
    const float mix0 = e0 * minv, mix1 = e1 * minv;

    float ss = 0.f;
    int i = blockIdx.x * 256 + tid;
    const int stride = gridDim.x * 256;
    for (; i < 65536; i += stride) {
        float dv = imp[i];
        float gbv = 0.f;
#pragma unroll
        for (int s = 0; s < 4; s++) {
            float H = rippleH(dv * invMA[s], beta, mix0, mix1);
            gbv += w[s] * H * invMA[s];
            ss += w[s] * H * dv * invA[s];
        }
        gmoe[i] = gbv;
    }
    red[tid] = ss; __syncthreads();
    for (int s = 128; s > 0; s >>= 1) { if (tid < s) red[tid] += red[tid + s]; __syncthreads(); }
    if (tid == 0) sspart[blockIdx.x] = red[0];
}

// moe softmin per batch row (4096); M/amax reduced inline from bmax/bidx[64]; sums sspart[64] inline
__global__ __launch_bounds__(256) void moe_sel_k(const float* __restrict__ gmoe, const float* __restrict__ bmax,
                                                 const int* __restrict__ bidx, const float* __restrict__ sspart,
                                                 float* __restrict__ sel) {
    __shared__ float red[256];
    const int tid = threadIdx.x;
    const int b = blockIdx.x;
    float M = -3.4e38f; int amax = 0x7FFFFFFF;
#pragma unroll
    for (int k = 0; k < 64; k++) {
        float v = bmax[k]; int ix = bidx[k];
        if (v > M || (v == M && ix < amax)) { M = v; amax = ix; }
    }
    float ssTot = 0.f;
#pragma unroll
    for (int k = 0; k < 64; k++) ssTot += sspart[k];
    const float corr = ssTot * rcp_(M * M);
    float g[16];
    float mn = 3.4e38f;
#pragma unroll
    for (int k = 0; k < 16; k++) {
        int i = b * 4096 + tid + k * 256;
        float v = gmoe[i];
        if (i == amax) v -= corr;
        v = fminf(fmaxf(v, -1.f), 1.f);
        g[k] = v;
        mn = fminf(mn, v);
    }
    red[tid] = mn; __syncthreads();
    for (int s = 128; s > 0; s >>= 1) { if (tid < s) red[tid] = fminf(red[tid], red[tid + s]); __syncthreads(); }
    mn = red[0]; __syncthreads();
    float sum = 0.f;
#pragma unroll
    for (int k = 0; k < 16; k++) { g[k] = fexp(mn - g[k]); sum += g[k]; }
    red[tid] = sum; __syncthreads();
    for (int s = 128; s > 0; s >>= 1) { if (tid < s) red[tid] += red[tid + s]; __syncthreads(); }
    float inv = rcp_(red[0]);
#pragma unroll
    for (int k = 0; k < 16; k++) sel[b * 4096 + tid + k * 256] = 1.f + g[k] * inv;
}

// ---------------- workspace layout (bytes) ----------------
static constexpr size_t OFF_XB    = 0;                       // ushort NE (attn: pvpart lower half; later probs2b)
static constexpr size_t OFF_TMPB  = 16777216;                // ushort NE (attn: pvpart upper half; later gsb)
static constexpr size_t OFF_SPB   = 33554432;                // ushort NE
static constexpr size_t OFF_SPT   = 50331648;                // ushort NE   ([4][512][4096])
static constexpr size_t OFF_DBUF  = 67108864;                // Sexp pair z=0 (32MB) / d1,attn bf16 / rankp
static constexpr size_t OFF_HBUF  = 100663296;               // Sexp pair z=1 (32MB) / gb bf16
static constexpr size_t OFF_GATB  = 134217728;               // ushort NE
static constexpr size_t OFF_NXB   = 150994944;               // ushort NE   (gxab)
static constexpr size_t OFF_EAB   = 167772160;               // ushort NE   (gaab)
static constexpr size_t OFF_AST   = 184549376;               // 512*512 ushort
static constexpr size_t OFF_WSP   = 185073664;
static constexpr size_t OFF_WSIL  = 185597952;
static constexpr size_t OFF_WOH   = 186122240;
static constexpr size_t OFF_WOUT  = 186646528;
static constexpr size_t OFF_WIGT  = 187170816;
static constexpr size_t OFF_WAGT  = 187301888;
static constexpr size_t OFF_POOL  = 187432960;               // 2048 uint
static constexpr size_t OFF_SCAL  = 187441152;               // 64 float (+ pmax u64[4] at +128)
static constexpr size_t OFF_SCALI = 187441408;
static constexpr size_t OFF_BMAX  = 187441664;
static constexpr size_t OFF_BIDX  = 187449856;
static constexpr size_t OFF_SSP   = 187458048;
static constexpr size_t OFF_COMB  = 187466240;               // 65536 float (attn: rowsum[2][8192])
static constexpr size_t OFF_VALS  = 187728384;
static constexpr size_t OFF_IMP   = 187990528;
static constexpr size_t OFF_GMOE  = 188252672;
static constexpr size_t OFF_SEL   = 188514816;
static constexpr size_t WS_NEED   = 188776960;

extern "C" void kernel_launch(void* const* d_in, const int* in_sizes, int n_in,
                              void* d_out, int out_size, void* d_ws, size_t ws_size,
                              hipStream_t stream)
{
    (void)in_sizes; (void)n_in; (void)out_size;
    const float* x    = (const float*)d_in[0];
    const float* AS   = (const float*)d_in[1];
    const float* Wsp  = (const float*)d_in[2];
    const float* Wsil = (const float*)d_in[3];
    const float* Woh  = (const float*)d_in[4];
    const float* Wout = (const float*)d_in[5];
    const float* wig  = (const float*)d_in[6];
    const float* wag  = (const float*)d_in[7];
    const float* a_param = (const float*)d_in[8];
    const float* cls_w = (const float*)d_in[9];
    const float* cls_b = (const float*)d_in[10];
    const float* tokw  = (const float*)d_in[11];
    const float* prelu = (const float*)d_in[12];
    const float* tsw   = (const float*)d_in[13];
    const float* tsa   = (const float*)d_in[14];
    const float* tsb   = (const float*)d_in[15];
    const float* tsmix = (const float*)d_in[16];
    const float* p1a = (const float*)d_in[17];
    const float* p1b = (const float*)d_in[18];
    const float* p1m = (const float*)d_in[19];
    const float* p2a = (const float*)d_in[20];
    const float* p2b = (const float*)d_in[21];
    const float* p2m = (const float*)d_in[22];
    float* out = (float*)d_out;

    char* w = (char*)d_ws;
    if (ws_size < WS_NEED) { sentinel_k<<<1, 256, 0, stream>>>(out); return; }

    ushort* xb    = (ushort*)(w + OFF_XB);
    ushort* tmpb  = (ushort*)(w + OFF_TMPB);
    ushort* spb   = (ushort*)(w + OFF_SPB);
    ushort* spT   = (ushort*)(w + OFF_SPT);
    ushort* db    = (ushort*)(w + OFF_DBUF);   // bf16 d1/attn buffer (ripple input)
    ushort* gbb   = (ushort*)(w + OFF_HBUF);   // bf16 gradient base (ripple passes)
    ushort* Spair = (ushort*)(w + OFF_DBUF);   // Sexp for batch pair: z*16777216 ushorts (64MB)
    ushort* pvpart= (ushort*)(w + OFF_XB);     // bf16 partials: [2 zb][4 ks][4096][512] (33.5MB XB+TMPB)
    int*    rankp = (int*)(w + OFF_DBUF);      // ts2 only
    ushort* gatedb= (ushort*)(w + OFF_GATB);
    ushort* gxab  = (ushort*)(w + OFF_NXB);
    ushort* gaab  = (ushort*)(w + OFF_EAB);
    ushort* ASt   = (ushort*)(w + OFF_AST);
    ushort* Wspb  = (ushort*)(w + OFF_WSP);
    ushort* Wsilb = (ushort*)(w + OFF_WSIL);
    ushort* Wohb  = (ushort*)(w + OFF_WOH);
    ushort* Woutb = (ushort*)(w + OFF_WOUT);
    ushort* wigT  = (ushort*)(w + OFF_WIGT);
    ushort* wagT  = (ushort*)(w + OFF_WAGT);
    uint*   poolU = (uint*)(w + OFF_POOL);
    float*  scal  = (float*)(w + OFF_SCAL);
    u64*    pmax  = (u64*)(w + OFF_SCAL + 128);
    float*  bmax  = (float*)(w + OFF_BMAX);
    int*    bidx  = (int*)(w + OFF_BIDX);
    float*  sspart= (float*)(w + OFF_SSP);
    float*  comb  = (float*)(w + OFF_COMB);
    float*  rowsum= comb;                      // [2][8192] during attention
    float*  vals  = (float*)(w + OFF_VALS);
    float*  imp   = (float*)(w + OFF_IMP);
    float*  gmoe  = (float*)(w + OFF_GMOE);
    float*  sel   = (float*)(w + OFF_SEL);
    ushort* gsb     = tmpb;
    ushort* probs2b = xb;

    // ---- prep ----
    convert_f2b_k<<<2048, 256, 0, stream>>>(x, xb, NE >> 2);
    convert_w4_k<<<dim3(256, 4), 256, 0, stream>>>(Wsp, Wsil, Woh, Wout, Wspb, poolU, pmax, rowsum, scal);
    transpose_to_bf16<true><<<dim3(16, 16, 1), 256, 0, stream>>>(AS, ASt, 512, 512);
    transpose_gates_k<<<dim3(4, 4, 8), 256, 0, stream>>>(wig, wag, wigT, wagT);

    // ---- merged G1 (tmp = xb @ ASt) + gate pre-act GEMMs ----
    g1gate_k<<<1536, 256, 0, stream>>>(xb, ASt, tmpb, wigT, wagT, gxab, gaab);

    // ---- G2: spatial = tmp @ Wsp^T ----
    gemm_bt<1, false><<<dim3(4, 128), 256, 0, stream>>>(tmpb, 512, Wspb, 512, spb, 512, 512, nullptr, nullptr);

    // ---- attention pool: batch pairs; 3 launches per pair ----
    transpose_to_bf16<false><<<dim3(16, 128, 4), 256, 0, stream>>>(spb, spT, 4096, 512);
    for (int p = 0; p < 2; p++) {
        const ushort* spP = spb + (size_t)(2 * p) * L_ * D_;
        gemm256_exp_k<<<dim3(16, 16, 2), 512, 0, stream>>>(spP, Spair, rowsum + p * 8192);
        pv_split_k<<<dim3(4, 32, 8), 256, 0, stream>>>(Spair, spT + (size_t)(2 * p) * D_ * L_, pvpart);
        pool_combine_k<<<dim3(128, 2), 256, 0, stream>>>(pvpart, rowsum + p * 8192, poolU + 2 * p * 512);
    }

    // ---- fused gates+gated ----
    gates_gated_k<<<1024, 256, 0, stream>>>(x, gxab, gaab, a_param, poolU, gatedb);

    // ---- sparsity = ripple_act(gated @ Wsil^T) ; gs = gated * sparsity ----
    gemm_bt<1, true><<<dim3(4, 128), 256, 0, stream>>>(gatedb, 512, Wsilb, 512, db, 512, 512, nullptr, &pmax[0]);
    ripple_g_k<<<2048, 256, 0, stream>>>(db, gbb, sspart, &pmax[0], p1a, p1b, p1m);
    redsum2_k<<<1, 256, 0, stream>>>(sspart, 2048, &scal[1]);
    ripple_softmax_k<1><<<4096, 256, 0, stream>>>(gbb, &pmax[0], &scal[1], p1a, gatedb, gsb);

    // ---- token selection -> sel ----
    ts1_k<<<4096, 256, 0, stream>>>(x, cls_w, cls_b, tokw, prelu, comb, vals);
    ts2a_k<<<dim3(16, 8, 4), 256, 0, stream>>>(comb, rankp);
    ts2b_k<<<dim3(16, 4), 256, 0, stream>>>(rankp, vals, imp, bmax, bidx);
    moe_g_k<<<64, 256, 0, stream>>>(imp, gmoe, sspart, bmax, tsw, tsa, tsb, tsmix);
    moe_sel_k<<<4, 256, 0, stream>>>(gmoe, bmax, bidx, sspart, sel);

    // ---- attn = gs @ Woh^T, scaled by sel (fused max; bf16 out) ----
    gemm_bt<3, true><<<dim3(4, 128), 256, 0, stream>>>(gsb, 512, Wohb, 512, db, 512, 512, sel, &pmax[1]);

    // ---- out_probs = ripple_act(d2) ----
    ripple_g_k<<<2048, 256, 0, stream>>>(db, gbb, sspart, &pmax[1], p2a, p2b, p2m);
    redsum2_k<<<1, 256, 0, stream>>>(sspart, 2048, &scal[3]);
    ripple_softmax_k<0><<<4096, 256, 0, stream>>>(gbb, &pmax[1], &scal[3], p2a, nullptr, probs2b);

    // ---- out = probs @ Wout^T ----
    gemm_bt<0, false><<<dim3(4, 128), 256, 0, stream>>>(probs2b, 512, Woutb, 512, out, 512, 512, nullptr, nullptr);
}